// Round 11
// baseline (523.136 us; speedup 1.0000x reference)
//
#include <hip/hip_runtime.h>

#define V_NODES 50000
#define FDIM    512   // B*Cin
#define CIN     128
#define COUT    128
#define BATCH   4
#define KORD    5
#define KTOT    (KORD * CIN)   // 640
#define SCAN_NBLK ((V_NODES + 255) / 256)   // 196

typedef short s16x8 __attribute__((ext_vector_type(8)));
typedef float f32x4 __attribute__((ext_vector_type(4)));
typedef int   i32x4 __attribute__((ext_vector_type(4)));

struct EPair { float w; int c; };   // interleaved edge: weight + col

__device__ __forceinline__ float bf2f(unsigned short u) {
    union { unsigned int i; float f; } x; x.i = ((unsigned int)u) << 16; return x.f;
}
__device__ __forceinline__ unsigned short f2bf(float f) {
    union { float f; unsigned int i; } x; x.f = f;
    unsigned int r = x.i + 0x7fffu + ((x.i >> 16) & 1u);   // RNE
    return (unsigned short)(r >> 16);
}

// ---------------- transpose: x (512, V) f32 -> T0 (V, 512) bf16 ------------
__global__ __launch_bounds__(256) void transpose_kernel(const float* __restrict__ x,
                                                        unsigned short* __restrict__ t0) {
    __shared__ float tile[64][65];
    const int v0 = blockIdx.x * 64;
    const int r0 = blockIdx.y * 64;
    const int lane = threadIdx.x & 63;
    const int w = threadIdx.x >> 6;
    #pragma unroll
    for (int i = 0; i < 16; ++i) {
        int rr = w * 16 + i;
        int v = v0 + lane;
        tile[rr][lane] = (v < V_NODES) ? x[(size_t)(r0 + rr) * V_NODES + v] : 0.0f;
    }
    __syncthreads();
    #pragma unroll
    for (int i = 0; i < 16; ++i) {
        int vv = w * 16 + i;
        int v = v0 + vv;
        if (v < V_NODES) t0[(size_t)v * FDIM + r0 + lane] = f2bf(tile[lane][vv]);
    }
}

// ---------------- W quantize: f32 [kci][co] -> i8 [co][kci] + scale [ord][co]
__global__ __launch_bounds__(256) void convw_q8_kernel(const float* __restrict__ W,
                                                       signed char* __restrict__ Wq8,
                                                       float* __restrict__ Wsc) {
    const int g = blockIdx.x * 4 + (threadIdx.x >> 6);   // group = ord*128+co
    if (g >= KORD * COUT) return;
    const int co = g & 127;
    const int ord = g >> 7;
    const int lane = threadIdx.x & 63;
    float w0 = W[(size_t)(ord * 128 + lane * 2 + 0) * COUT + co];
    float w1 = W[(size_t)(ord * 128 + lane * 2 + 1) * COUT + co];
    float m = fmaxf(fabsf(w0), fabsf(w1));
    #pragma unroll
    for (int off = 1; off < 64; off <<= 1) m = fmaxf(m, __shfl_xor(m, off, 64));
    float inv = (m > 0.f) ? 127.f / m : 0.f;
    int q0 = max(-127, min(127, (int)rintf(w0 * inv)));
    int q1 = max(-127, min(127, (int)rintf(w1 * inv)));
    unsigned short pk = (unsigned short)((q0 & 0xff) | ((q1 & 0xff) << 8));
    *(unsigned short*)(Wq8 + (size_t)co * KTOT + ord * 128 + lane * 2) = pk;
    if (lane == 0) Wsc[ord * 128 + co] = m / 127.f;
}

// ---------------- CSR build ------------------------------------------------
__global__ __launch_bounds__(256) void hist_kernel(const int* __restrict__ rows,
                                                   int* __restrict__ cnt, int E) {
    int e = blockIdx.x * 256 + threadIdx.x;
    if (e < E) atomicAdd(&cnt[rows[e]], 1);
}

__global__ __launch_bounds__(256) void scan1_kernel(const int* __restrict__ cnt,
                                                    int* __restrict__ rowPtr,
                                                    int* __restrict__ blkSum) {
    __shared__ int sh[256];
    const int t = threadIdx.x;
    const int i = blockIdx.x * 256 + t;
    int v = (i < V_NODES) ? cnt[i] : 0;
    sh[t] = v;
    __syncthreads();
    #pragma unroll
    for (int off = 1; off < 256; off <<= 1) {
        int u = (t >= off) ? sh[t - off] : 0;
        __syncthreads();
        sh[t] += u;
        __syncthreads();
    }
    if (i < V_NODES) rowPtr[i] = sh[t] - v;
    if (t == 255) blkSum[blockIdx.x] = sh[255];
}

__global__ __launch_bounds__(256) void scan23_kernel(const int* __restrict__ blkSum,
                                                     int* __restrict__ rowPtr,
                                                     int* __restrict__ cursor) {
    __shared__ int sh[256];
    const int t = threadIdx.x;
    int v = (t < SCAN_NBLK) ? blkSum[t] : 0;
    sh[t] = v;
    __syncthreads();
    #pragma unroll
    for (int off = 1; off < 256; off <<= 1) {
        int u = (t >= off) ? sh[t - off] : 0;
        __syncthreads();
        sh[t] += u;
        __syncthreads();
    }
    const int boff = sh[blockIdx.x] - blkSum[blockIdx.x];
    const int i = blockIdx.x * 256 + t;
    if (i < V_NODES) {
        int r = rowPtr[i] + boff;
        rowPtr[i] = r;
        cursor[i] = r;
    }
    if (blockIdx.x == 0 && t == 255) rowPtr[V_NODES] = sh[255];
}

__global__ __launch_bounds__(256) void scatter_kernel(const float* __restrict__ vals,
                                                      const int* __restrict__ rows,
                                                      const int* __restrict__ cols,
                                                      int* __restrict__ cursor,
                                                      EPair* __restrict__ ep, int E) {
    int e = blockIdx.x * 256 + threadIdx.x;
    if (e >= E) return;
    int r = rows[e];
    int pos = atomicAdd(&cursor[r], 1);
    EPair p; p.w = vals[e]; p.c = cols[e];
    ep[pos] = p;
}

// ---------------- quantize bf16 rows -> int8 + per-row scale ---------------
__global__ __launch_bounds__(256) void quant_rows_kernel(const unsigned short* __restrict__ xb,
                                                         signed char* __restrict__ xi,
                                                         float* __restrict__ xs) {
    const int wid = threadIdx.x >> 6;
    const int lane = threadIdx.x & 63;
    const int row = blockIdx.x * 4 + wid;
    if (row >= V_NODES) return;
    uint4 q = ((const uint4*)xb)[(size_t)row * 64 + lane];
    unsigned int u[4] = {q.x, q.y, q.z, q.w};
    float f[8];
    #pragma unroll
    for (int j = 0; j < 4; ++j) {
        f[2*j+0] = bf2f((unsigned short)(u[j] & 0xffffu));
        f[2*j+1] = bf2f((unsigned short)(u[j] >> 16));
    }
    float m = 0.f;
    #pragma unroll
    for (int j = 0; j < 8; ++j) m = fmaxf(m, fabsf(f[j]));
    #pragma unroll
    for (int off = 1; off < 64; off <<= 1) m = fmaxf(m, __shfl_xor(m, off, 64));
    float inv = (m > 0.f) ? 127.f / m : 0.f;
    uint2 o; unsigned int ow[2] = {0u, 0u};
    #pragma unroll
    for (int j = 0; j < 8; ++j) {
        int si = (int)rintf(f[j] * inv);
        si = max(-127, min(127, si));
        ow[j >> 2] |= ((unsigned int)(si & 0xff)) << (8 * (j & 3));
    }
    o.x = ow[0]; o.y = ow[1];
    ((uint2*)xi)[(size_t)row * 64 + lane] = o;
    if (lane == 0) xs[row] = m / 127.f;
}

// ---------------- CSR SpMM: i8 in, i8 out -----------------------------------
__global__ __launch_bounds__(256) void spmm_i8_kernel(const EPair* __restrict__ ep,
                                                      const int* __restrict__ rowPtr,
                                                      const signed char* __restrict__ xi,
                                                      const float* __restrict__ xsc,
                                                      const signed char* __restrict__ oldi,
                                                      const float* __restrict__ oldsc,
                                                      signed char* __restrict__ yi,
                                                      float* __restrict__ ysc,
                                                      float alpha, int beta) {
    const int wid = threadIdx.x >> 6;
    const int lane = threadIdx.x & 63;
    const int row = blockIdx.x * 4 + wid;
    if (row >= V_NODES) return;
    const int s = rowPtr[row], e_end = rowPtr[row + 1];
    const uint2* __restrict__ xq = (const uint2*)xi;   // 64 x 8B per row

    float acc[8];
    #pragma unroll
    for (int j = 0; j < 8; ++j) acc[j] = 0.f;

    int e = s;
    for (; e + 3 < e_end; e += 4) {
        EPair p[4];
        #pragma unroll
        for (int i = 0; i < 4; ++i) p[i] = ep[e + i];
        float w[4];
        #pragma unroll
        for (int i = 0; i < 4; ++i) w[i] = p[i].w * xsc[p[i].c];
        uint2 q[4];
        #pragma unroll
        for (int i = 0; i < 4; ++i) q[i] = xq[(size_t)p[i].c * 64 + lane];
        #pragma unroll
        for (int i = 0; i < 4; ++i) {
            #pragma unroll
            for (int wd = 0; wd < 2; ++wd) {
                unsigned int uu = wd ? q[i].y : q[i].x;
                #pragma unroll
                for (int b = 0; b < 4; ++b) {
                    float xv = (float)((signed char)(uu >> (8 * b)));
                    acc[wd * 4 + b] += w[i] * xv;
                }
            }
        }
    }
    for (; e < e_end; ++e) {
        EPair p0 = ep[e];
        float w0 = p0.w * xsc[p0.c];
        uint2 q0 = xq[(size_t)p0.c * 64 + lane];
        #pragma unroll
        for (int wd = 0; wd < 2; ++wd) {
            unsigned int uu = wd ? q0.y : q0.x;
            #pragma unroll
            for (int b = 0; b < 4; ++b) {
                float xv = (float)((signed char)(uu >> (8 * b)));
                acc[wd * 4 + b] += w0 * xv;
            }
        }
    }

    float r[8];
    #pragma unroll
    for (int j = 0; j < 8; ++j) r[j] = alpha * acc[j];
    if (beta) {
        uint2 q = ((const uint2*)oldi)[(size_t)row * 64 + lane];
        const float os = oldsc[row];
        #pragma unroll
        for (int wd = 0; wd < 2; ++wd) {
            unsigned int uu = wd ? q.y : q.x;
            #pragma unroll
            for (int b = 0; b < 4; ++b)
                r[wd * 4 + b] -= os * (float)((signed char)(uu >> (8 * b)));
        }
    }

    float m = 0.f;
    #pragma unroll
    for (int j = 0; j < 8; ++j) m = fmaxf(m, fabsf(r[j]));
    #pragma unroll
    for (int off = 1; off < 64; off <<= 1) m = fmaxf(m, __shfl_xor(m, off, 64));
    float inv = (m > 0.f) ? 127.f / m : 0.f;
    unsigned int ow[2] = {0u, 0u};
    #pragma unroll
    for (int j = 0; j < 8; ++j) {
        int si = (int)rintf(r[j] * inv);
        si = max(-127, min(127, si));
        ow[j >> 2] |= ((unsigned int)(si & 0xff)) << (8 * (j & 3));
    }
    uint2 oi; oi.x = ow[0]; oi.y = ow[1];
    ((uint2*)yi)[(size_t)row * 64 + lane] = oi;
    if (lane == 0) ysc[row] = m / 127.f;
}

// ---------------- fused i8-MFMA GEMM over all K orders ----------------------
// A from i8 T via 3-deep LDS ring (glds, rotation chunk-swizzle, b128 reads);
// B i8 direct global; i32 MFMA accumulate, f32 rescale per order.
__global__ __launch_bounds__(256) void gemm_mfma_kernel(const signed char* __restrict__ Ti8,
                                                        const float* __restrict__ Tsc,
                                                        const signed char* __restrict__ Wq8,
                                                        const float* __restrict__ Wsc,
                                                        const float* __restrict__ bias,
                                                        float* __restrict__ out) {
    __shared__ signed char Abuf[3][128 * 64];   // 3 x 8 KB ring
    const int lane = threadIdx.x & 63;
    const int wv = threadIdx.x >> 6;
    const int v0 = blockIdx.x * 128;
    const int b = blockIdx.y;
    const int lr = lane & 15;
    const int lk = lane >> 4;

    // staging: 2 glds/thread/step. flat -> row_local = flat>>2, phys chunk = flat&3.
    // rotation swizzle: phys chunk P holds logical chunk (P - (rl>>1)) & 3.
    size_t gofB[2];
    #pragma unroll
    for (int j = 0; j < 2; ++j) {
        int flat = j * 256 + (int)threadIdx.x;
        int rl = flat >> 2;
        int ch = flat & 3;
        int rowg = v0 + rl;
        if (rowg >= V_NODES) rowg = V_NODES - 1;
        int srcch = (ch - ((rl >> 1) & 3)) & 3;
        gofB[j] = (size_t)rowg * FDIM + b * CIN + (size_t)(srcch << 4);
    }

    f32x4 accF[8][2];
    i32x4 accI[8][2];
    #pragma unroll
    for (int mf = 0; mf < 8; ++mf)
        #pragma unroll
        for (int nf = 0; nf < 2; ++nf) {
            accF[mf][nf] = (f32x4){0.f, 0.f, 0.f, 0.f};
            accI[mf][nf] = (i32x4){0, 0, 0, 0};
        }

    const signed char* Bb = Wq8 + (size_t)(wv * 32 + lr) * KTOT + lk * 16;

    // prologue: stage steps 0,1 into slots 0,1
    #pragma unroll
    for (int st = 0; st < 2; ++st) {
        const size_t soff = (size_t)(st & 1) * 64;   // steps 0,1 are order 0
        #pragma unroll
        for (int j = 0; j < 2; ++j)
            __builtin_amdgcn_global_load_lds(
                (const __attribute__((address_space(1))) void*)(Ti8 + gofB[j] + soff),
                (__attribute__((address_space(3))) void*)(&Abuf[st][(j * 256 + (int)threadIdx.x) * 16]),
                16, 0, 0);
    }
    asm volatile("s_waitcnt vmcnt(2)" ::: "memory");
    asm volatile("s_barrier" ::: "memory");

    int curm = 0, stm = 2;
    #pragma unroll 1
    for (int s = 0; s < 10; ++s) {
        // 1) B fragment + (odd step) rescale-factor loads — issued FIRST
        i32x4 bcur[2];
        #pragma unroll
        for (int nf = 0; nf < 2; ++nf)
            bcur[nf] = *(const i32x4*)(Bb + (size_t)nf * 16 * KTOT + s * 64);
        f32x4 sv[8];
        float swv[2];
        const int ord = s >> 1;
        if (s & 1) {
            #pragma unroll
            for (int mf = 0; mf < 8; ++mf) {
                int base = v0 + mf * 16 + lk * 4;
                if (base > V_NODES - 4) base = V_NODES - 4;
                sv[mf] = *(const f32x4*)(Tsc + (size_t)ord * V_NODES + base);
            }
            swv[0] = Wsc[ord * 128 + wv * 32 + lr];
            swv[1] = Wsc[ord * 128 + wv * 32 + 16 + lr];
        }
        __builtin_amdgcn_sched_barrier(0);
        // 2) stage step s+2 (stays in flight across compute + barrier)
        if (s < 8) {
            const int sn = s + 2;
            const size_t soff = (size_t)(sn >> 1) * ((size_t)V_NODES * FDIM) + (size_t)((sn & 1) * 64);
            #pragma unroll
            for (int j = 0; j < 2; ++j)
                __builtin_amdgcn_global_load_lds(
                    (const __attribute__((address_space(1))) void*)(Ti8 + gofB[j] + soff),
                    (__attribute__((address_space(3))) void*)(&Abuf[stm][(j * 256 + (int)threadIdx.x) * 16]),
                    16, 0, 0);
        }
        // 3) compute: b128 swizzled reads -> i8 MFMA (K=64)
        const signed char* Ab = &Abuf[curm][0];
        i32x4 a[8];
        #pragma unroll
        for (int mf = 0; mf < 8; ++mf) {
            int rl = mf * 16 + lr;
            int phys = rl * 64 + (((lk + (rl >> 1)) & 3) << 4);
            a[mf] = *(const i32x4*)(Ab + phys);
        }
        #pragma unroll
        for (int mf = 0; mf < 8; ++mf)
            #pragma unroll
            for (int nf = 0; nf < 2; ++nf)
                accI[mf][nf] = __builtin_amdgcn_mfma_i32_16x16x64_i8(a[mf], bcur[nf], accI[mf][nf], 0, 0, 0);
        // 4) order boundary: rescale i32 -> f32 and reset
        if (s & 1) {
            #pragma unroll
            for (int mf = 0; mf < 8; ++mf)
                #pragma unroll
                for (int nf = 0; nf < 2; ++nf) {
                    #pragma unroll
                    for (int e = 0; e < 4; ++e)
                        accF[mf][nf][e] += (float)accI[mf][nf][e] * (sv[mf][e] * swv[nf]);
                    accI[mf][nf] = (i32x4){0, 0, 0, 0};
                }
        }
        asm volatile("s_barrier" ::: "memory");
        curm = (curm == 2) ? 0 : curm + 1;
        stm  = (stm == 2) ? 0 : stm + 1;
    }

    // --- epilogue: transpose through LDS (reuse ring), coalesced f32x4 stores
    float* lds_f = (float*)&Abuf[0][0];            // 32 co x 132 f32 = 16.9 KB < 24 KB
    const float bs0 = bias[wv * 32 + lr];
    const float bs1 = bias[wv * 32 + 16 + lr];
    #pragma unroll
    for (int p = 0; p < 4; ++p) {
        if (wv == p) {
            #pragma unroll
            for (int mf = 0; mf < 8; ++mf)
                #pragma unroll
                for (int nf = 0; nf < 2; ++nf) {
                    int co_l = nf * 16 + lr;
                    int vbase = mf * 16 + lk * 4;
                    f32x4 val = accF[mf][nf];
                    float bs = nf ? bs1 : bs0;
                    val[0] += bs; val[1] += bs; val[2] += bs; val[3] += bs;
                    *(f32x4*)(lds_f + co_l * 132 + vbase) = val;
                }
        }
        __syncthreads();
        #pragma unroll
        for (int i = 0; i < 4; ++i) {
            int flat = i * 256 + threadIdx.x;
            int co_l = flat >> 5;
            int v4 = flat & 31;
            int v = v0 + v4 * 4;
            if (v < V_NODES) {
                f32x4 val = *(const f32x4*)(lds_f + co_l * 132 + v4 * 4);
                *(f32x4*)(out + (size_t)(b * COUT + p * 32 + co_l) * V_NODES + v) = val;
            }
        }
        __syncthreads();
    }
}

extern "C" void kernel_launch(void* const* d_in, const int* in_sizes, int n_in,
                              void* d_out, int out_size, void* d_ws, size_t ws_size,
                              hipStream_t stream) {
    const float* x    = (const float*)d_in[0];
    const float* vals = (const float*)d_in[1];
    const float* W    = (const float*)d_in[2];
    const float* bias = (const float*)d_in[3];
    const int* rows   = (const int*)d_in[4];
    const int* cols   = (const int*)d_in[5];
    const int E = in_sizes[1];
    float* out = (float*)d_out;

    // workspace: bf16 T0 scratch, i8 T0..T4, scales (+pad), Wq8, Wsc, edges, CSR
    unsigned short* T0bf = (unsigned short*)d_ws;                      // V*512 bf16
    signed char* i8T = (signed char*)(T0bf + (size_t)V_NODES * FDIM);  // 5 * V*512
    float* sc  = (float*)(i8T + (size_t)KORD * V_NODES * FDIM);        // 5*V + 64 pad
    signed char* Wq8 = (signed char*)(sc + (size_t)KORD * V_NODES + 64);  // 128*640
    float* Wsc = (float*)(Wq8 + (size_t)COUT * KTOT);                  // 640
    EPair* ep     = (EPair*)(Wsc + KORD * COUT);
    int*   rowPtr = (int*)(ep + E);
    int*   cursor = rowPtr + V_NODES + 1;
    int*   cnt    = cursor + V_NODES;
    int*   blkSum = cnt + V_NODES;            // SCAN_NBLK

    signed char* i8T0 = i8T;
    signed char* i8T1 = i8T + 1 * (size_t)V_NODES * FDIM;
    signed char* i8T2 = i8T + 2 * (size_t)V_NODES * FDIM;
    signed char* i8T3 = i8T + 3 * (size_t)V_NODES * FDIM;
    signed char* i8T4 = i8T + 4 * (size_t)V_NODES * FDIM;
    float* sc0 = sc + 0 * (size_t)V_NODES;
    float* sc1 = sc + 1 * (size_t)V_NODES;
    float* sc2 = sc + 2 * (size_t)V_NODES;
    float* sc3 = sc + 3 * (size_t)V_NODES;
    float* sc4 = sc + 4 * (size_t)V_NODES;

    const int eBlocks = (E + 255) / 256;
    const int spB4 = (V_NODES + 3) / 4;

    // CSR build
    hipMemsetAsync(cnt, 0, V_NODES * sizeof(int), stream);
    hist_kernel<<<eBlocks, 256, 0, stream>>>(rows, cnt, E);
    scan1_kernel<<<SCAN_NBLK, 256, 0, stream>>>(cnt, rowPtr, blkSum);
    scan23_kernel<<<SCAN_NBLK, 256, 0, stream>>>(blkSum, rowPtr, cursor);
    scatter_kernel<<<eBlocks, 256, 0, stream>>>(vals, rows, cols, cursor, ep, E);

    // T0 + weights
    dim3 tg((V_NODES + 63) / 64, FDIM / 64);
    transpose_kernel<<<tg, 256, 0, stream>>>(x, T0bf);
    convw_q8_kernel<<<(KORD * COUT + 3) / 4, 256, 0, stream>>>(W, Wq8, Wsc);
    quant_rows_kernel<<<spB4, 256, 0, stream>>>(T0bf, i8T0, sc0);

    // Chebyshev recurrence — all state in i8 + per-row scale
    spmm_i8_kernel<<<spB4, 256, 0, stream>>>(ep, rowPtr, i8T0, sc0, i8T0, sc0, i8T1, sc1, 1.f, 0);
    spmm_i8_kernel<<<spB4, 256, 0, stream>>>(ep, rowPtr, i8T1, sc1, i8T0, sc0, i8T2, sc2, 2.f, 1);
    spmm_i8_kernel<<<spB4, 256, 0, stream>>>(ep, rowPtr, i8T2, sc2, i8T1, sc1, i8T3, sc3, 2.f, 1);
    spmm_i8_kernel<<<spB4, 256, 0, stream>>>(ep, rowPtr, i8T3, sc3, i8T2, sc2, i8T4, sc4, 2.f, 1);

    // fused contraction over all 5 orders (i8 MFMA)
    dim3 gg((V_NODES + 127) / 128, BATCH);
    gemm_mfma_kernel<<<gg, 256, 0, stream>>>(i8T, sc, Wq8, Wsc, bias, out);
}

// Round 12
// 496.110 us; speedup vs baseline: 1.0545x; 1.0545x over previous
//
#include <hip/hip_runtime.h>

#define V_NODES 50000
#define FDIM    512   // B*Cin
#define CIN     128
#define COUT    128
#define BATCH   4
#define KORD    5
#define KTOT    (KORD * CIN)   // 640
#define SCAN_NBLK ((V_NODES + 255) / 256)   // 196

typedef short s16x8 __attribute__((ext_vector_type(8)));
typedef float f32x4 __attribute__((ext_vector_type(4)));
typedef int   i32x4 __attribute__((ext_vector_type(4)));

struct EPair { float w; int c; };   // interleaved edge: weight + col

__device__ __forceinline__ float bf2f(unsigned short u) {
    union { unsigned int i; float f; } x; x.i = ((unsigned int)u) << 16; return x.f;
}
__device__ __forceinline__ unsigned short f2bf(float f) {
    union { float f; unsigned int i; } x; x.f = f;
    unsigned int r = x.i + 0x7fffu + ((x.i >> 16) & 1u);   // RNE
    return (unsigned short)(r >> 16);
}

// ---------------- transpose: x (512, V) f32 -> T0 (V, 512) bf16 ------------
__global__ __launch_bounds__(256) void transpose_kernel(const float* __restrict__ x,
                                                        unsigned short* __restrict__ t0) {
    __shared__ float tile[64][65];
    const int v0 = blockIdx.x * 64;
    const int r0 = blockIdx.y * 64;
    const int lane = threadIdx.x & 63;
    const int w = threadIdx.x >> 6;
    #pragma unroll
    for (int i = 0; i < 16; ++i) {
        int rr = w * 16 + i;
        int v = v0 + lane;
        tile[rr][lane] = (v < V_NODES) ? x[(size_t)(r0 + rr) * V_NODES + v] : 0.0f;
    }
    __syncthreads();
    #pragma unroll
    for (int i = 0; i < 16; ++i) {
        int vv = w * 16 + i;
        int v = v0 + vv;
        if (v < V_NODES) t0[(size_t)v * FDIM + r0 + lane] = f2bf(tile[lane][vv]);
    }
}

// ---------------- W quantize: f32 [kci][co] -> i8 [co][kci] + scale [ord][co]
__global__ __launch_bounds__(256) void convw_q8_kernel(const float* __restrict__ W,
                                                       signed char* __restrict__ Wq8,
                                                       float* __restrict__ Wsc) {
    const int g = blockIdx.x * 4 + (threadIdx.x >> 6);   // group = ord*128+co
    if (g >= KORD * COUT) return;
    const int co = g & 127;
    const int ord = g >> 7;
    const int lane = threadIdx.x & 63;
    float w0 = W[(size_t)(ord * 128 + lane * 2 + 0) * COUT + co];
    float w1 = W[(size_t)(ord * 128 + lane * 2 + 1) * COUT + co];
    float m = fmaxf(fabsf(w0), fabsf(w1));
    #pragma unroll
    for (int off = 1; off < 64; off <<= 1) m = fmaxf(m, __shfl_xor(m, off, 64));
    float inv = (m > 0.f) ? 127.f / m : 0.f;
    int q0 = max(-127, min(127, (int)rintf(w0 * inv)));
    int q1 = max(-127, min(127, (int)rintf(w1 * inv)));
    unsigned short pk = (unsigned short)((q0 & 0xff) | ((q1 & 0xff) << 8));
    *(unsigned short*)(Wq8 + (size_t)co * KTOT + ord * 128 + lane * 2) = pk;
    if (lane == 0) Wsc[ord * 128 + co] = m / 127.f;
}

// ---------------- CSR build ------------------------------------------------
__global__ __launch_bounds__(256) void hist_kernel(const int* __restrict__ rows,
                                                   int* __restrict__ cnt, int E) {
    int e = blockIdx.x * 256 + threadIdx.x;
    if (e < E) atomicAdd(&cnt[rows[e]], 1);
}

__global__ __launch_bounds__(256) void scan1_kernel(const int* __restrict__ cnt,
                                                    int* __restrict__ rowPtr,
                                                    int* __restrict__ blkSum) {
    __shared__ int sh[256];
    const int t = threadIdx.x;
    const int i = blockIdx.x * 256 + t;
    int v = (i < V_NODES) ? cnt[i] : 0;
    sh[t] = v;
    __syncthreads();
    #pragma unroll
    for (int off = 1; off < 256; off <<= 1) {
        int u = (t >= off) ? sh[t - off] : 0;
        __syncthreads();
        sh[t] += u;
        __syncthreads();
    }
    if (i < V_NODES) rowPtr[i] = sh[t] - v;
    if (t == 255) blkSum[blockIdx.x] = sh[255];
}

__global__ __launch_bounds__(256) void scan23_kernel(const int* __restrict__ blkSum,
                                                     int* __restrict__ rowPtr,
                                                     int* __restrict__ cursor) {
    __shared__ int sh[256];
    const int t = threadIdx.x;
    int v = (t < SCAN_NBLK) ? blkSum[t] : 0;
    sh[t] = v;
    __syncthreads();
    #pragma unroll
    for (int off = 1; off < 256; off <<= 1) {
        int u = (t >= off) ? sh[t - off] : 0;
        __syncthreads();
        sh[t] += u;
        __syncthreads();
    }
    const int boff = sh[blockIdx.x] - blkSum[blockIdx.x];
    const int i = blockIdx.x * 256 + t;
    if (i < V_NODES) {
        int r = rowPtr[i] + boff;
        rowPtr[i] = r;
        cursor[i] = r;
    }
    if (blockIdx.x == 0 && t == 255) rowPtr[V_NODES] = sh[255];
}

__global__ __launch_bounds__(256) void scatter_kernel(const float* __restrict__ vals,
                                                      const int* __restrict__ rows,
                                                      const int* __restrict__ cols,
                                                      int* __restrict__ cursor,
                                                      EPair* __restrict__ ep, int E) {
    int e = blockIdx.x * 256 + threadIdx.x;
    if (e >= E) return;
    int r = rows[e];
    int pos = atomicAdd(&cursor[r], 1);
    EPair p; p.w = vals[e]; p.c = cols[e];
    ep[pos] = p;
}

// ---------------- quantize bf16 rows -> int8 + per-row scale ---------------
__global__ __launch_bounds__(256) void quant_rows_kernel(const unsigned short* __restrict__ xb,
                                                         signed char* __restrict__ xi,
                                                         float* __restrict__ xs) {
    const int wid = threadIdx.x >> 6;
    const int lane = threadIdx.x & 63;
    const int row = blockIdx.x * 4 + wid;
    if (row >= V_NODES) return;
    uint4 q = ((const uint4*)xb)[(size_t)row * 64 + lane];
    unsigned int u[4] = {q.x, q.y, q.z, q.w};
    float f[8];
    #pragma unroll
    for (int j = 0; j < 4; ++j) {
        f[2*j+0] = bf2f((unsigned short)(u[j] & 0xffffu));
        f[2*j+1] = bf2f((unsigned short)(u[j] >> 16));
    }
    float m = 0.f;
    #pragma unroll
    for (int j = 0; j < 8; ++j) m = fmaxf(m, fabsf(f[j]));
    #pragma unroll
    for (int off = 1; off < 64; off <<= 1) m = fmaxf(m, __shfl_xor(m, off, 64));
    float inv = (m > 0.f) ? 127.f / m : 0.f;
    uint2 o; unsigned int ow[2] = {0u, 0u};
    #pragma unroll
    for (int j = 0; j < 8; ++j) {
        int si = (int)rintf(f[j] * inv);
        si = max(-127, min(127, si));
        ow[j >> 2] |= ((unsigned int)(si & 0xff)) << (8 * (j & 3));
    }
    o.x = ow[0]; o.y = ow[1];
    ((uint2*)xi)[(size_t)row * 64 + lane] = o;
    if (lane == 0) xs[row] = m / 127.f;
}

// ---------------- CSR SpMM: i8 in, i8 out -----------------------------------
__global__ __launch_bounds__(256) void spmm_i8_kernel(const EPair* __restrict__ ep,
                                                      const int* __restrict__ rowPtr,
                                                      const signed char* __restrict__ xi,
                                                      const float* __restrict__ xsc,
                                                      const signed char* __restrict__ oldi,
                                                      const float* __restrict__ oldsc,
                                                      signed char* __restrict__ yi,
                                                      float* __restrict__ ysc,
                                                      float alpha, int beta) {
    const int wid = threadIdx.x >> 6;
    const int lane = threadIdx.x & 63;
    const int row = blockIdx.x * 4 + wid;
    if (row >= V_NODES) return;
    const int s = rowPtr[row], e_end = rowPtr[row + 1];
    const uint2* __restrict__ xq = (const uint2*)xi;   // 64 x 8B per row

    float acc[8];
    #pragma unroll
    for (int j = 0; j < 8; ++j) acc[j] = 0.f;

    int e = s;
    for (; e + 3 < e_end; e += 4) {
        EPair p[4];
        #pragma unroll
        for (int i = 0; i < 4; ++i) p[i] = ep[e + i];
        float w[4];
        #pragma unroll
        for (int i = 0; i < 4; ++i) w[i] = p[i].w * xsc[p[i].c];
        uint2 q[4];
        #pragma unroll
        for (int i = 0; i < 4; ++i) q[i] = xq[(size_t)p[i].c * 64 + lane];
        #pragma unroll
        for (int i = 0; i < 4; ++i) {
            #pragma unroll
            for (int wd = 0; wd < 2; ++wd) {
                unsigned int uu = wd ? q[i].y : q[i].x;
                #pragma unroll
                for (int b = 0; b < 4; ++b) {
                    float xv = (float)((signed char)(uu >> (8 * b)));
                    acc[wd * 4 + b] += w[i] * xv;
                }
            }
        }
    }
    for (; e < e_end; ++e) {
        EPair p0 = ep[e];
        float w0 = p0.w * xsc[p0.c];
        uint2 q0 = xq[(size_t)p0.c * 64 + lane];
        #pragma unroll
        for (int wd = 0; wd < 2; ++wd) {
            unsigned int uu = wd ? q0.y : q0.x;
            #pragma unroll
            for (int b = 0; b < 4; ++b) {
                float xv = (float)((signed char)(uu >> (8 * b)));
                acc[wd * 4 + b] += w0 * xv;
            }
        }
    }

    float r[8];
    #pragma unroll
    for (int j = 0; j < 8; ++j) r[j] = alpha * acc[j];
    if (beta) {
        uint2 q = ((const uint2*)oldi)[(size_t)row * 64 + lane];
        const float os = oldsc[row];
        #pragma unroll
        for (int wd = 0; wd < 2; ++wd) {
            unsigned int uu = wd ? q.y : q.x;
            #pragma unroll
            for (int b = 0; b < 4; ++b)
                r[wd * 4 + b] -= os * (float)((signed char)(uu >> (8 * b)));
        }
    }

    float m = 0.f;
    #pragma unroll
    for (int j = 0; j < 8; ++j) m = fmaxf(m, fabsf(r[j]));
    #pragma unroll
    for (int off = 1; off < 64; off <<= 1) m = fmaxf(m, __shfl_xor(m, off, 64));
    float inv = (m > 0.f) ? 127.f / m : 0.f;
    unsigned int ow[2] = {0u, 0u};
    #pragma unroll
    for (int j = 0; j < 8; ++j) {
        int si = (int)rintf(r[j] * inv);
        si = max(-127, min(127, si));
        ow[j >> 2] |= ((unsigned int)(si & 0xff)) << (8 * (j & 3));
    }
    uint2 oi; oi.x = ow[0]; oi.y = ow[1];
    ((uint2*)yi)[(size_t)row * 64 + lane] = oi;
    if (lane == 0) ysc[row] = m / 127.f;
}

// ---------------- fused i8-MFMA GEMM, 8 waves (2v x 4co) --------------------
// A from i8 T via 3-deep LDS ring (glds, rotation chunk-swizzle, b128 reads);
// B i8 direct global; i32 MFMA accumulate, f32 rescale per order.
// Per wave: 64 rows x 32 cols -> accI[4][2]+accF[4][2] = 64 VGPR.
__global__ __launch_bounds__(512) void gemm_mfma_kernel(const signed char* __restrict__ Ti8,
                                                        const float* __restrict__ Tsc,
                                                        const signed char* __restrict__ Wq8,
                                                        const float* __restrict__ Wsc,
                                                        const float* __restrict__ bias,
                                                        float* __restrict__ out) {
    __shared__ signed char Abuf[3][128 * 64];   // 3 x 8 KB ring
    const int tid = threadIdx.x;
    const int lane = tid & 63;
    const int wid = tid >> 6;        // 0..7
    const int wr = wid >> 2;         // 0..1: v-half
    const int wc = wid & 3;          // 0..3: co-quarter
    const int v0 = blockIdx.x * 128;
    const int b = blockIdx.y;
    const int lr = lane & 15;
    const int lk = lane >> 4;

    // staging: 1 glds/thread. dest = tid*16 (linear); source chunk rotated.
    size_t gof;
    {
        int rl = tid >> 2;           // 0..127
        int ch = tid & 3;
        int rowg = v0 + rl;
        if (rowg >= V_NODES) rowg = V_NODES - 1;
        int srcch = (ch - ((rl >> 1) & 3)) & 3;
        gof = (size_t)rowg * FDIM + b * CIN + (size_t)(srcch << 4);
    }

    f32x4 accF[4][2];
    i32x4 accI[4][2];
    #pragma unroll
    for (int mf = 0; mf < 4; ++mf)
        #pragma unroll
        for (int nf = 0; nf < 2; ++nf) {
            accF[mf][nf] = (f32x4){0.f, 0.f, 0.f, 0.f};
            accI[mf][nf] = (i32x4){0, 0, 0, 0};
        }

    const signed char* Bb = Wq8 + (size_t)(wc * 32 + lr) * KTOT + lk * 16;

    // prologue: stage steps 0,1 into slots 0,1 (1 glds instr per wave per step)
    #pragma unroll
    for (int st = 0; st < 2; ++st) {
        const size_t soff = (size_t)(st & 1) * 64;   // steps 0,1 are order 0
        __builtin_amdgcn_global_load_lds(
            (const __attribute__((address_space(1))) void*)(Ti8 + gof + soff),
            (__attribute__((address_space(3))) void*)(&Abuf[st][tid * 16]),
            16, 0, 0);
    }
    asm volatile("s_waitcnt vmcnt(1)" ::: "memory");
    asm volatile("s_barrier" ::: "memory");

    int curm = 0, stm = 2;
    #pragma unroll 1
    for (int s = 0; s < 10; ++s) {
        // 1) B fragment + (odd step) rescale-factor loads — issued FIRST
        i32x4 bcur[2];
        #pragma unroll
        for (int nf = 0; nf < 2; ++nf)
            bcur[nf] = *(const i32x4*)(Bb + (size_t)nf * 16 * KTOT + s * 64);
        f32x4 sv[4];
        float swv[2];
        const int ord = s >> 1;
        if (s & 1) {
            #pragma unroll
            for (int mf = 0; mf < 4; ++mf) {
                int base = v0 + wr * 64 + mf * 16 + lk * 4;
                if (base > V_NODES - 4) base = V_NODES - 4;
                sv[mf] = *(const f32x4*)(Tsc + (size_t)ord * V_NODES + base);
            }
            swv[0] = Wsc[ord * 128 + wc * 32 + lr];
            swv[1] = Wsc[ord * 128 + wc * 32 + 16 + lr];
        }
        __builtin_amdgcn_sched_barrier(0);
        // 2) stage step s+2 (stays in flight across compute + barrier)
        if (s < 8) {
            const int sn = s + 2;
            const size_t soff = (size_t)(sn >> 1) * ((size_t)V_NODES * FDIM) + (size_t)((sn & 1) * 64);
            __builtin_amdgcn_global_load_lds(
                (const __attribute__((address_space(1))) void*)(Ti8 + gof + soff),
                (__attribute__((address_space(3))) void*)(&Abuf[stm][tid * 16]),
                16, 0, 0);
        }
        // 3) compute: b128 rotated reads -> i8 MFMA (K=64)
        const signed char* Ab = &Abuf[curm][0];
        i32x4 a[4];
        #pragma unroll
        for (int mf = 0; mf < 4; ++mf) {
            int rl = wr * 64 + mf * 16 + lr;
            int phys = rl * 64 + (((lk + (rl >> 1)) & 3) << 4);
            a[mf] = *(const i32x4*)(Ab + phys);
        }
        #pragma unroll
        for (int mf = 0; mf < 4; ++mf)
            #pragma unroll
            for (int nf = 0; nf < 2; ++nf)
                accI[mf][nf] = __builtin_amdgcn_mfma_i32_16x16x64_i8(a[mf], bcur[nf], accI[mf][nf], 0, 0, 0);
        // 4) order boundary: rescale i32 -> f32 and reset
        if (s & 1) {
            #pragma unroll
            for (int mf = 0; mf < 4; ++mf)
                #pragma unroll
                for (int nf = 0; nf < 2; ++nf) {
                    #pragma unroll
                    for (int e = 0; e < 4; ++e)
                        accF[mf][nf][e] += (float)accI[mf][nf][e] * (sv[mf][e] * swv[nf]);
                    accI[mf][nf] = (i32x4){0, 0, 0, 0};
                }
        }
        asm volatile("s_barrier" ::: "memory");
        curm = (curm == 2) ? 0 : curm + 1;
        stm  = (stm == 2) ? 0 : stm + 1;
    }

    // --- epilogue: transpose through LDS (reuse ring), coalesced f32x4 stores
    float* lds_f = (float*)&Abuf[0][0];            // 32 co x 132 f32 = 16.9 KB < 24 KB
    const float bs0 = bias[wc * 32 + lr];
    const float bs1 = bias[wc * 32 + 16 + lr];
    #pragma unroll
    for (int p = 0; p < 4; ++p) {
        if (wc == p) {
            #pragma unroll
            for (int mf = 0; mf < 4; ++mf)
                #pragma unroll
                for (int nf = 0; nf < 2; ++nf) {
                    int co_l = nf * 16 + lr;
                    int vbase = wr * 64 + mf * 16 + lk * 4;
                    f32x4 val = accF[mf][nf];
                    float bs = nf ? bs1 : bs0;
                    val[0] += bs; val[1] += bs; val[2] += bs; val[3] += bs;
                    *(f32x4*)(lds_f + co_l * 132 + vbase) = val;
                }
        }
        __syncthreads();
        #pragma unroll
        for (int i = 0; i < 2; ++i) {
            int flat = i * 512 + tid;
            int co_l = flat >> 5;
            int v4 = flat & 31;
            int v = v0 + v4 * 4;
            if (v < V_NODES) {
                f32x4 val = *(const f32x4*)(lds_f + co_l * 132 + v4 * 4);
                *(f32x4*)(out + (size_t)(b * COUT + p * 32 + co_l) * V_NODES + v) = val;
            }
        }
        __syncthreads();
    }
}

extern "C" void kernel_launch(void* const* d_in, const int* in_sizes, int n_in,
                              void* d_out, int out_size, void* d_ws, size_t ws_size,
                              hipStream_t stream) {
    const float* x    = (const float*)d_in[0];
    const float* vals = (const float*)d_in[1];
    const float* W    = (const float*)d_in[2];
    const float* bias = (const float*)d_in[3];
    const int* rows   = (const int*)d_in[4];
    const int* cols   = (const int*)d_in[5];
    const int E = in_sizes[1];
    float* out = (float*)d_out;

    // workspace: bf16 T0 scratch, i8 T0..T4, scales (+pad), Wq8, Wsc, edges, CSR
    unsigned short* T0bf = (unsigned short*)d_ws;                      // V*512 bf16
    signed char* i8T = (signed char*)(T0bf + (size_t)V_NODES * FDIM);  // 5 * V*512
    float* sc  = (float*)(i8T + (size_t)KORD * V_NODES * FDIM);        // 5*V + 64 pad
    signed char* Wq8 = (signed char*)(sc + (size_t)KORD * V_NODES + 64);  // 128*640
    float* Wsc = (float*)(Wq8 + (size_t)COUT * KTOT);                  // 640
    EPair* ep     = (EPair*)(Wsc + KORD * COUT);
    int*   rowPtr = (int*)(ep + E);
    int*   cursor = rowPtr + V_NODES + 1;
    int*   cnt    = cursor + V_NODES;
    int*   blkSum = cnt + V_NODES;            // SCAN_NBLK

    signed char* i8T0 = i8T;
    signed char* i8T1 = i8T + 1 * (size_t)V_NODES * FDIM;
    signed char* i8T2 = i8T + 2 * (size_t)V_NODES * FDIM;
    signed char* i8T3 = i8T + 3 * (size_t)V_NODES * FDIM;
    signed char* i8T4 = i8T + 4 * (size_t)V_NODES * FDIM;
    float* sc0 = sc + 0 * (size_t)V_NODES;
    float* sc1 = sc + 1 * (size_t)V_NODES;
    float* sc2 = sc + 2 * (size_t)V_NODES;
    float* sc3 = sc + 3 * (size_t)V_NODES;
    float* sc4 = sc + 4 * (size_t)V_NODES;

    const int eBlocks = (E + 255) / 256;
    const int spB4 = (V_NODES + 3) / 4;

    // CSR build
    hipMemsetAsync(cnt, 0, V_NODES * sizeof(int), stream);
    hist_kernel<<<eBlocks, 256, 0, stream>>>(rows, cnt, E);
    scan1_kernel<<<SCAN_NBLK, 256, 0, stream>>>(cnt, rowPtr, blkSum);
    scan23_kernel<<<SCAN_NBLK, 256, 0, stream>>>(blkSum, rowPtr, cursor);
    scatter_kernel<<<eBlocks, 256, 0, stream>>>(vals, rows, cols, cursor, ep, E);

    // T0 + weights
    dim3 tg((V_NODES + 63) / 64, FDIM / 64);
    transpose_kernel<<<tg, 256, 0, stream>>>(x, T0bf);
    convw_q8_kernel<<<(KORD * COUT + 3) / 4, 256, 0, stream>>>(W, Wq8, Wsc);
    quant_rows_kernel<<<spB4, 256, 0, stream>>>(T0bf, i8T0, sc0);

    // Chebyshev recurrence — all state in i8 + per-row scale
    spmm_i8_kernel<<<spB4, 256, 0, stream>>>(ep, rowPtr, i8T0, sc0, i8T0, sc0, i8T1, sc1, 1.f, 0);
    spmm_i8_kernel<<<spB4, 256, 0, stream>>>(ep, rowPtr, i8T1, sc1, i8T0, sc0, i8T2, sc2, 2.f, 1);
    spmm_i8_kernel<<<spB4, 256, 0, stream>>>(ep, rowPtr, i8T2, sc2, i8T1, sc1, i8T3, sc3, 2.f, 1);
    spmm_i8_kernel<<<spB4, 256, 0, stream>>>(ep, rowPtr, i8T3, sc3, i8T2, sc2, i8T4, sc4, 2.f, 1);

    // fused contraction over all 5 orders (i8 MFMA, 8 waves)
    dim3 gg((V_NODES + 127) / 128, BATCH);
    gemm_mfma_kernel<<<gg, 512, 0, stream>>>(i8T, sc, Wq8, Wsc, bias, out);
}

// Round 13
// 490.544 us; speedup vs baseline: 1.0664x; 1.0113x over previous
//
#include <hip/hip_runtime.h>

#define V_NODES 50000
#define FDIM    512   // B*Cin
#define CIN     128
#define COUT    128
#define BATCH   4
#define KORD    5
#define KTOT    (KORD * CIN)   // 640
#define SCAN_NBLK ((V_NODES + 255) / 256)   // 196

typedef short s16x8 __attribute__((ext_vector_type(8)));
typedef float f32x4 __attribute__((ext_vector_type(4)));
typedef int   i32x4 __attribute__((ext_vector_type(4)));

struct EPair { float w; int c; };   // interleaved edge: weight + col

__device__ __forceinline__ float bf2f(unsigned short u) {
    union { unsigned int i; float f; } x; x.i = ((unsigned int)u) << 16; return x.f;
}
__device__ __forceinline__ unsigned short f2bf(float f) {
    union { float f; unsigned int i; } x; x.f = f;
    unsigned int r = x.i + 0x7fffu + ((x.i >> 16) & 1u);   // RNE
    return (unsigned short)(r >> 16);
}

// ---------------- transpose: x (512, V) f32 -> T0 (V, 512) bf16 ------------
__global__ __launch_bounds__(256) void transpose_kernel(const float* __restrict__ x,
                                                        unsigned short* __restrict__ t0) {
    __shared__ float tile[64][65];
    const int v0 = blockIdx.x * 64;
    const int r0 = blockIdx.y * 64;
    const int lane = threadIdx.x & 63;
    const int w = threadIdx.x >> 6;
    #pragma unroll
    for (int i = 0; i < 16; ++i) {
        int rr = w * 16 + i;
        int v = v0 + lane;
        tile[rr][lane] = (v < V_NODES) ? x[(size_t)(r0 + rr) * V_NODES + v] : 0.0f;
    }
    __syncthreads();
    #pragma unroll
    for (int i = 0; i < 16; ++i) {
        int vv = w * 16 + i;
        int v = v0 + vv;
        if (v < V_NODES) t0[(size_t)v * FDIM + r0 + lane] = f2bf(tile[lane][vv]);
    }
}

// ---------------- W quantize: f32 [kci][co] -> i8 [co][kci] + scale [ord][co]
__global__ __launch_bounds__(256) void convw_q8_kernel(const float* __restrict__ W,
                                                       signed char* __restrict__ Wq8,
                                                       float* __restrict__ Wsc) {
    const int g = blockIdx.x * 4 + (threadIdx.x >> 6);   // group = ord*128+co
    if (g >= KORD * COUT) return;
    const int co = g & 127;
    const int ord = g >> 7;
    const int lane = threadIdx.x & 63;
    float w0 = W[(size_t)(ord * 128 + lane * 2 + 0) * COUT + co];
    float w1 = W[(size_t)(ord * 128 + lane * 2 + 1) * COUT + co];
    float m = fmaxf(fabsf(w0), fabsf(w1));
    #pragma unroll
    for (int off = 1; off < 64; off <<= 1) m = fmaxf(m, __shfl_xor(m, off, 64));
    float inv = (m > 0.f) ? 127.f / m : 0.f;
    int q0 = max(-127, min(127, (int)rintf(w0 * inv)));
    int q1 = max(-127, min(127, (int)rintf(w1 * inv)));
    unsigned short pk = (unsigned short)((q0 & 0xff) | ((q1 & 0xff) << 8));
    *(unsigned short*)(Wq8 + (size_t)co * KTOT + ord * 128 + lane * 2) = pk;
    if (lane == 0) Wsc[ord * 128 + co] = m / 127.f;
}

// ---------------- CSR build ------------------------------------------------
__global__ __launch_bounds__(256) void hist_kernel(const int* __restrict__ rows,
                                                   int* __restrict__ cnt, int E) {
    int e = blockIdx.x * 256 + threadIdx.x;
    if (e < E) atomicAdd(&cnt[rows[e]], 1);
}

__global__ __launch_bounds__(256) void scan1_kernel(const int* __restrict__ cnt,
                                                    int* __restrict__ rowPtr,
                                                    int* __restrict__ blkSum) {
    __shared__ int sh[256];
    const int t = threadIdx.x;
    const int i = blockIdx.x * 256 + t;
    int v = (i < V_NODES) ? cnt[i] : 0;
    sh[t] = v;
    __syncthreads();
    #pragma unroll
    for (int off = 1; off < 256; off <<= 1) {
        int u = (t >= off) ? sh[t - off] : 0;
        __syncthreads();
        sh[t] += u;
        __syncthreads();
    }
    if (i < V_NODES) rowPtr[i] = sh[t] - v;
    if (t == 255) blkSum[blockIdx.x] = sh[255];
}

__global__ __launch_bounds__(256) void scan23_kernel(const int* __restrict__ blkSum,
                                                     int* __restrict__ rowPtr,
                                                     int* __restrict__ cursor) {
    __shared__ int sh[256];
    const int t = threadIdx.x;
    int v = (t < SCAN_NBLK) ? blkSum[t] : 0;
    sh[t] = v;
    __syncthreads();
    #pragma unroll
    for (int off = 1; off < 256; off <<= 1) {
        int u = (t >= off) ? sh[t - off] : 0;
        __syncthreads();
        sh[t] += u;
        __syncthreads();
    }
    const int boff = sh[blockIdx.x] - blkSum[blockIdx.x];
    const int i = blockIdx.x * 256 + t;
    if (i < V_NODES) {
        int r = rowPtr[i] + boff;
        rowPtr[i] = r;
        cursor[i] = r;
    }
    if (blockIdx.x == 0 && t == 255) rowPtr[V_NODES] = sh[255];
}

__global__ __launch_bounds__(256) void scatter_kernel(const float* __restrict__ vals,
                                                      const int* __restrict__ rows,
                                                      const int* __restrict__ cols,
                                                      int* __restrict__ cursor,
                                                      EPair* __restrict__ ep, int E) {
    int e = blockIdx.x * 256 + threadIdx.x;
    if (e >= E) return;
    int r = rows[e];
    int pos = atomicAdd(&cursor[r], 1);
    EPair p; p.w = vals[e]; p.c = cols[e];
    ep[pos] = p;
}

// ---------------- quantize bf16 rows -> int8 + per-row scale ---------------
__global__ __launch_bounds__(256) void quant_rows_kernel(const unsigned short* __restrict__ xb,
                                                         signed char* __restrict__ xi,
                                                         float* __restrict__ xs) {
    const int wid = threadIdx.x >> 6;
    const int lane = threadIdx.x & 63;
    const int row = blockIdx.x * 4 + wid;
    if (row >= V_NODES) return;
    uint4 q = ((const uint4*)xb)[(size_t)row * 64 + lane];
    unsigned int u[4] = {q.x, q.y, q.z, q.w};
    float f[8];
    #pragma unroll
    for (int j = 0; j < 4; ++j) {
        f[2*j+0] = bf2f((unsigned short)(u[j] & 0xffffu));
        f[2*j+1] = bf2f((unsigned short)(u[j] >> 16));
    }
    float m = 0.f;
    #pragma unroll
    for (int j = 0; j < 8; ++j) m = fmaxf(m, fabsf(f[j]));
    #pragma unroll
    for (int off = 1; off < 64; off <<= 1) m = fmaxf(m, __shfl_xor(m, off, 64));
    float inv = (m > 0.f) ? 127.f / m : 0.f;
    uint2 o; unsigned int ow[2] = {0u, 0u};
    #pragma unroll
    for (int j = 0; j < 8; ++j) {
        int si = (int)rintf(f[j] * inv);
        si = max(-127, min(127, si));
        ow[j >> 2] |= ((unsigned int)(si & 0xff)) << (8 * (j & 3));
    }
    o.x = ow[0]; o.y = ow[1];
    ((uint2*)xi)[(size_t)row * 64 + lane] = o;
    if (lane == 0) xs[row] = m / 127.f;
}

// ---------------- CSR SpMM: i8 in, i8 out -----------------------------------
__global__ __launch_bounds__(256) void spmm_i8_kernel(const EPair* __restrict__ ep,
                                                      const int* __restrict__ rowPtr,
                                                      const signed char* __restrict__ xi,
                                                      const float* __restrict__ xsc,
                                                      const signed char* __restrict__ oldi,
                                                      const float* __restrict__ oldsc,
                                                      signed char* __restrict__ yi,
                                                      float* __restrict__ ysc,
                                                      float alpha, int beta) {
    const int wid = threadIdx.x >> 6;
    const int lane = threadIdx.x & 63;
    const int row = blockIdx.x * 4 + wid;
    if (row >= V_NODES) return;
    const int s = rowPtr[row], e_end = rowPtr[row + 1];
    const uint2* __restrict__ xq = (const uint2*)xi;   // 64 x 8B per row

    float acc[8];
    #pragma unroll
    for (int j = 0; j < 8; ++j) acc[j] = 0.f;

    int e = s;
    for (; e + 3 < e_end; e += 4) {
        EPair p[4];
        #pragma unroll
        for (int i = 0; i < 4; ++i) p[i] = ep[e + i];
        float w[4];
        #pragma unroll
        for (int i = 0; i < 4; ++i) w[i] = p[i].w * xsc[p[i].c];
        uint2 q[4];
        #pragma unroll
        for (int i = 0; i < 4; ++i) q[i] = xq[(size_t)p[i].c * 64 + lane];
        #pragma unroll
        for (int i = 0; i < 4; ++i) {
            #pragma unroll
            for (int wd = 0; wd < 2; ++wd) {
                unsigned int uu = wd ? q[i].y : q[i].x;
                #pragma unroll
                for (int b = 0; b < 4; ++b) {
                    float xv = (float)((signed char)(uu >> (8 * b)));
                    acc[wd * 4 + b] += w[i] * xv;
                }
            }
        }
    }
    for (; e < e_end; ++e) {
        EPair p0 = ep[e];
        float w0 = p0.w * xsc[p0.c];
        uint2 q0 = xq[(size_t)p0.c * 64 + lane];
        #pragma unroll
        for (int wd = 0; wd < 2; ++wd) {
            unsigned int uu = wd ? q0.y : q0.x;
            #pragma unroll
            for (int b = 0; b < 4; ++b) {
                float xv = (float)((signed char)(uu >> (8 * b)));
                acc[wd * 4 + b] += w0 * xv;
            }
        }
    }

    float r[8];
    #pragma unroll
    for (int j = 0; j < 8; ++j) r[j] = alpha * acc[j];
    if (beta) {
        uint2 q = ((const uint2*)oldi)[(size_t)row * 64 + lane];
        const float os = oldsc[row];
        #pragma unroll
        for (int wd = 0; wd < 2; ++wd) {
            unsigned int uu = wd ? q.y : q.x;
            #pragma unroll
            for (int b = 0; b < 4; ++b)
                r[wd * 4 + b] -= os * (float)((signed char)(uu >> (8 * b)));
        }
    }

    float m = 0.f;
    #pragma unroll
    for (int j = 0; j < 8; ++j) m = fmaxf(m, fabsf(r[j]));
    #pragma unroll
    for (int off = 1; off < 64; off <<= 1) m = fmaxf(m, __shfl_xor(m, off, 64));
    float inv = (m > 0.f) ? 127.f / m : 0.f;
    unsigned int ow[2] = {0u, 0u};
    #pragma unroll
    for (int j = 0; j < 8; ++j) {
        int si = (int)rintf(r[j] * inv);
        si = max(-127, min(127, si));
        ow[j >> 2] |= ((unsigned int)(si & 0xff)) << (8 * (j & 3));
    }
    uint2 oi; oi.x = ow[0]; oi.y = ow[1];
    ((uint2*)yi)[(size_t)row * 64 + lane] = oi;
    if (lane == 0) ysc[row] = m / 127.f;
}

// ---------------- fused i8-MFMA GEMM, 8 waves (2v x 4co) --------------------
// A from i8 T via 3-deep LDS ring (glds, rotation chunk-swizzle, b128 reads).
// B fragments + rescale factors prefetched ONE ITERATION AHEAD so the only
// pre-MFMA wait is the A lgkmcnt; the end-of-iteration bnxt->bcur copy drains
// B(s+1) and stage(s+1), giving the A-stage a full 2-iteration latency cover.
__global__ __launch_bounds__(512) void gemm_mfma_kernel(const signed char* __restrict__ Ti8,
                                                        const float* __restrict__ Tsc,
                                                        const signed char* __restrict__ Wq8,
                                                        const float* __restrict__ Wsc,
                                                        const float* __restrict__ bias,
                                                        float* __restrict__ out) {
    __shared__ signed char Abuf[3][128 * 64];   // 3 x 8 KB ring
    const int tid = threadIdx.x;
    const int lane = tid & 63;
    const int wid = tid >> 6;        // 0..7
    const int wr = wid >> 2;         // 0..1: v-half
    const int wc = wid & 3;          // 0..3: co-quarter
    const int v0 = blockIdx.x * 128;
    const int b = blockIdx.y;
    const int lr = lane & 15;
    const int lk = lane >> 4;

    // staging: 1 glds/thread. dest = tid*16 (linear); source chunk rotated.
    size_t gof;
    {
        int rl = tid >> 2;           // 0..127
        int ch = tid & 3;
        int rowg = v0 + rl;
        if (rowg >= V_NODES) rowg = V_NODES - 1;
        int srcch = (ch - ((rl >> 1) & 3)) & 3;
        gof = (size_t)rowg * FDIM + b * CIN + (size_t)(srcch << 4);
    }

    f32x4 accF[4][2];
    i32x4 accI[4][2];
    #pragma unroll
    for (int mf = 0; mf < 4; ++mf)
        #pragma unroll
        for (int nf = 0; nf < 2; ++nf) {
            accF[mf][nf] = (f32x4){0.f, 0.f, 0.f, 0.f};
            accI[mf][nf] = (i32x4){0, 0, 0, 0};
        }

    const signed char* Bb = Wq8 + (size_t)(wc * 32 + lr) * KTOT + lk * 16;

    // prologue: stage steps 0,1; preload B(0)
    #pragma unroll
    for (int st = 0; st < 2; ++st) {
        const size_t soff = (size_t)(st & 1) * 64;   // steps 0,1 are order 0
        __builtin_amdgcn_global_load_lds(
            (const __attribute__((address_space(1))) void*)(Ti8 + gof + soff),
            (__attribute__((address_space(3))) void*)(&Abuf[st][tid * 16]),
            16, 0, 0);
    }
    i32x4 bcur[2];
    #pragma unroll
    for (int nf = 0; nf < 2; ++nf)
        bcur[nf] = *(const i32x4*)(Bb + (size_t)nf * 16 * KTOT);
    f32x4 sv[4];
    float swv0 = 0.f, swv1 = 0.f;
    asm volatile("s_waitcnt vmcnt(0)" ::: "memory");
    asm volatile("s_barrier" ::: "memory");

    int curm = 0, stm = 2;
    #pragma unroll 1
    for (int s = 0; s < 10; ++s) {
        // 1) prefetch B(s+1) into registers (8 VGPR, i8)
        i32x4 bnxt[2];
        if (s < 9) {
            #pragma unroll
            for (int nf = 0; nf < 2; ++nf)
                bnxt[nf] = *(const i32x4*)(Bb + (size_t)nf * 16 * KTOT + (s + 1) * 64);
        }
        // 2) even steps: prefetch rescale factors used at step s+1 (ord = s/2)
        if (!(s & 1)) {
            const int ord = s >> 1;
            #pragma unroll
            for (int mf = 0; mf < 4; ++mf) {
                int base = v0 + wr * 64 + mf * 16 + lk * 4;
                if (base > V_NODES - 4) base = V_NODES - 4;
                sv[mf] = *(const f32x4*)(Tsc + (size_t)ord * V_NODES + base);
            }
            swv0 = Wsc[ord * 128 + wc * 32 + lr];
            swv1 = Wsc[ord * 128 + wc * 32 + 16 + lr];
        }
        __builtin_amdgcn_sched_barrier(0);
        // 3) stage step s+2 (stays in flight two iterations)
        if (s < 8) {
            const int sn = s + 2;
            const size_t soff = (size_t)(sn >> 1) * ((size_t)V_NODES * FDIM) + (size_t)((sn & 1) * 64);
            __builtin_amdgcn_global_load_lds(
                (const __attribute__((address_space(1))) void*)(Ti8 + gof + soff),
                (__attribute__((address_space(3))) void*)(&Abuf[stm][tid * 16]),
                16, 0, 0);
        }
        // 4) compute: b128 rotated A reads -> i8 MFMA with bcur (registers)
        const signed char* Ab = &Abuf[curm][0];
        i32x4 a[4];
        #pragma unroll
        for (int mf = 0; mf < 4; ++mf) {
            int rl = wr * 64 + mf * 16 + lr;
            int phys = rl * 64 + (((lk + (rl >> 1)) & 3) << 4);
            a[mf] = *(const i32x4*)(Ab + phys);
        }
        #pragma unroll
        for (int mf = 0; mf < 4; ++mf)
            #pragma unroll
            for (int nf = 0; nf < 2; ++nf)
                accI[mf][nf] = __builtin_amdgcn_mfma_i32_16x16x64_i8(a[mf], bcur[nf], accI[mf][nf], 0, 0, 0);
        // 5) order boundary: rescale i32 -> f32 (factors prefetched at s-1)
        if (s & 1) {
            #pragma unroll
            for (int mf = 0; mf < 4; ++mf)
                #pragma unroll
                for (int nf = 0; nf < 2; ++nf) {
                    float sw = nf ? swv1 : swv0;
                    #pragma unroll
                    for (int e = 0; e < 4; ++e)
                        accF[mf][nf][e] += (float)accI[mf][nf][e] * (sv[mf][e] * sw);
                    accI[mf][nf] = (i32x4){0, 0, 0, 0};
                }
        }
        // 6) copy prefetched B (compiler's wait here drains B(s+1)+stage(s+1))
        if (s < 9) {
            bcur[0] = bnxt[0];
            bcur[1] = bnxt[1];
        }
        asm volatile("s_barrier" ::: "memory");
        curm = (curm == 2) ? 0 : curm + 1;
        stm  = (stm == 2) ? 0 : stm + 1;
    }

    // --- epilogue: transpose through LDS (reuse ring), coalesced f32x4 stores
    float* lds_f = (float*)&Abuf[0][0];            // 32 co x 132 f32 = 16.9 KB < 24 KB
    const float bs0 = bias[wc * 32 + lr];
    const float bs1 = bias[wc * 32 + 16 + lr];
    #pragma unroll
    for (int p = 0; p < 4; ++p) {
        if (wc == p) {
            #pragma unroll
            for (int mf = 0; mf < 4; ++mf)
                #pragma unroll
                for (int nf = 0; nf < 2; ++nf) {
                    int co_l = nf * 16 + lr;
                    int vbase = wr * 64 + mf * 16 + lk * 4;
                    f32x4 val = accF[mf][nf];
                    float bs = nf ? bs1 : bs0;
                    val[0] += bs; val[1] += bs; val[2] += bs; val[3] += bs;
                    *(f32x4*)(lds_f + co_l * 132 + vbase) = val;
                }
        }
        __syncthreads();
        #pragma unroll
        for (int i = 0; i < 2; ++i) {
            int flat = i * 512 + tid;
            int co_l = flat >> 5;
            int v4 = flat & 31;
            int v = v0 + v4 * 4;
            if (v < V_NODES) {
                f32x4 val = *(const f32x4*)(lds_f + co_l * 132 + v4 * 4);
                *(f32x4*)(out + (size_t)(b * COUT + p * 32 + co_l) * V_NODES + v) = val;
            }
        }
        __syncthreads();
    }
}

extern "C" void kernel_launch(void* const* d_in, const int* in_sizes, int n_in,
                              void* d_out, int out_size, void* d_ws, size_t ws_size,
                              hipStream_t stream) {
    const float* x    = (const float*)d_in[0];
    const float* vals = (const float*)d_in[1];
    const float* W    = (const float*)d_in[2];
    const float* bias = (const float*)d_in[3];
    const int* rows   = (const int*)d_in[4];
    const int* cols   = (const int*)d_in[5];
    const int E = in_sizes[1];
    float* out = (float*)d_out;

    // workspace: bf16 T0 scratch, i8 T0..T4, scales (+pad), Wq8, Wsc, edges, CSR
    unsigned short* T0bf = (unsigned short*)d_ws;                      // V*512 bf16
    signed char* i8T = (signed char*)(T0bf + (size_t)V_NODES * FDIM);  // 5 * V*512
    float* sc  = (float*)(i8T + (size_t)KORD * V_NODES * FDIM);        // 5*V + 64 pad
    signed char* Wq8 = (signed char*)(sc + (size_t)KORD * V_NODES + 64);  // 128*640
    float* Wsc = (float*)(Wq8 + (size_t)COUT * KTOT);                  // 640
    EPair* ep     = (EPair*)(Wsc + KORD * COUT);
    int*   rowPtr = (int*)(ep + E);
    int*   cursor = rowPtr + V_NODES + 1;
    int*   cnt    = cursor + V_NODES;
    int*   blkSum = cnt + V_NODES;            // SCAN_NBLK

    signed char* i8T0 = i8T;
    signed char* i8T1 = i8T + 1 * (size_t)V_NODES * FDIM;
    signed char* i8T2 = i8T + 2 * (size_t)V_NODES * FDIM;
    signed char* i8T3 = i8T + 3 * (size_t)V_NODES * FDIM;
    signed char* i8T4 = i8T + 4 * (size_t)V_NODES * FDIM;
    float* sc0 = sc + 0 * (size_t)V_NODES;
    float* sc1 = sc + 1 * (size_t)V_NODES;
    float* sc2 = sc + 2 * (size_t)V_NODES;
    float* sc3 = sc + 3 * (size_t)V_NODES;
    float* sc4 = sc + 4 * (size_t)V_NODES;

    const int eBlocks = (E + 255) / 256;
    const int spB4 = (V_NODES + 3) / 4;

    // CSR build
    hipMemsetAsync(cnt, 0, V_NODES * sizeof(int), stream);
    hist_kernel<<<eBlocks, 256, 0, stream>>>(rows, cnt, E);
    scan1_kernel<<<SCAN_NBLK, 256, 0, stream>>>(cnt, rowPtr, blkSum);
    scan23_kernel<<<SCAN_NBLK, 256, 0, stream>>>(blkSum, rowPtr, cursor);
    scatter_kernel<<<eBlocks, 256, 0, stream>>>(vals, rows, cols, cursor, ep, E);

    // T0 + weights
    dim3 tg((V_NODES + 63) / 64, FDIM / 64);
    transpose_kernel<<<tg, 256, 0, stream>>>(x, T0bf);
    convw_q8_kernel<<<(KORD * COUT + 3) / 4, 256, 0, stream>>>(W, Wq8, Wsc);
    quant_rows_kernel<<<spB4, 256, 0, stream>>>(T0bf, i8T0, sc0);

    // Chebyshev recurrence — all state in i8 + per-row scale
    spmm_i8_kernel<<<spB4, 256, 0, stream>>>(ep, rowPtr, i8T0, sc0, i8T0, sc0, i8T1, sc1, 1.f, 0);
    spmm_i8_kernel<<<spB4, 256, 0, stream>>>(ep, rowPtr, i8T1, sc1, i8T0, sc0, i8T2, sc2, 2.f, 1);
    spmm_i8_kernel<<<spB4, 256, 0, stream>>>(ep, rowPtr, i8T2, sc2, i8T1, sc1, i8T3, sc3, 2.f, 1);
    spmm_i8_kernel<<<spB4, 256, 0, stream>>>(ep, rowPtr, i8T3, sc3, i8T2, sc2, i8T4, sc4, 2.f, 1);

    // fused contraction over all 5 orders (i8 MFMA, 8 waves)
    dim3 gg((V_NODES + 127) / 128, BATCH);
    gemm_mfma_kernel<<<gg, 512, 0, stream>>>(i8T, sc, Wq8, Wsc, bias, out);
}

// Round 14
// 489.006 us; speedup vs baseline: 1.0698x; 1.0031x over previous
//
#include <hip/hip_runtime.h>

#define V_NODES 50000
#define FDIM    512   // B*Cin
#define CIN     128
#define COUT    128
#define BATCH   4
#define KORD    5
#define KTOT    (KORD * CIN)   // 640
#define SCAN_NBLK ((V_NODES + 255) / 256)   // 196
#define TR_BLOCKS (((V_NODES + 63) / 64) * (FDIM / 64))   // 782*8 = 6256
#define CONVW_BLOCKS ((KORD * COUT + 3) / 4)              // 160
#define QUANT_BLOCKS ((V_NODES + 3) / 4)                  // 12500

typedef short s16x8 __attribute__((ext_vector_type(8)));
typedef float f32x4 __attribute__((ext_vector_type(4)));
typedef int   i32x4 __attribute__((ext_vector_type(4)));

struct EPair { float w; int c; };   // interleaved edge: weight + col

__device__ __forceinline__ float bf2f(unsigned short u) {
    union { unsigned int i; float f; } x; x.i = ((unsigned int)u) << 16; return x.f;
}
__device__ __forceinline__ unsigned short f2bf(float f) {
    union { float f; unsigned int i; } x; x.f = f;
    unsigned int r = x.i + 0x7fffu + ((x.i >> 16) & 1u);   // RNE
    return (unsigned short)(r >> 16);
}

// ---------------- prep1: transpose ∥ hist ∥ convw_q8 (block-range dispatch) --
__global__ __launch_bounds__(256) void prep1_kernel(const float* __restrict__ x,
                                                    unsigned short* __restrict__ t0,
                                                    const int* __restrict__ rows,
                                                    int* __restrict__ cnt,
                                                    int E, int histBlocks,
                                                    const float* __restrict__ W,
                                                    signed char* __restrict__ Wq8,
                                                    float* __restrict__ Wsc) {
    __shared__ float tile[64][65];
    const int bid = blockIdx.x;
    if (bid < TR_BLOCKS) {
        // ---- transpose: x (512, V) f32 -> T0 (V, 512) bf16 ----
        const int v0 = (bid % ((V_NODES + 63) / 64)) * 64;
        const int r0 = (bid / ((V_NODES + 63) / 64)) * 64;
        const int lane = threadIdx.x & 63;
        const int w = threadIdx.x >> 6;
        #pragma unroll
        for (int i = 0; i < 16; ++i) {
            int rr = w * 16 + i;
            int v = v0 + lane;
            tile[rr][lane] = (v < V_NODES) ? x[(size_t)(r0 + rr) * V_NODES + v] : 0.0f;
        }
        __syncthreads();
        #pragma unroll
        for (int i = 0; i < 16; ++i) {
            int vv = w * 16 + i;
            int v = v0 + vv;
            if (v < V_NODES) t0[(size_t)v * FDIM + r0 + lane] = f2bf(tile[lane][vv]);
        }
    } else if (bid < TR_BLOCKS + histBlocks) {
        // ---- hist ----
        int e = (bid - TR_BLOCKS) * 256 + threadIdx.x;
        if (e < E) atomicAdd(&cnt[rows[e]], 1);
    } else {
        // ---- W quantize: f32 [kci][co] -> i8 [co][kci] + scale [ord][co] ----
        const int g = (bid - TR_BLOCKS - histBlocks) * 4 + (threadIdx.x >> 6);
        if (g >= KORD * COUT) return;
        const int co = g & 127;
        const int ord = g >> 7;
        const int lane = threadIdx.x & 63;
        float w0 = W[(size_t)(ord * 128 + lane * 2 + 0) * COUT + co];
        float w1 = W[(size_t)(ord * 128 + lane * 2 + 1) * COUT + co];
        float m = fmaxf(fabsf(w0), fabsf(w1));
        #pragma unroll
        for (int off = 1; off < 64; off <<= 1) m = fmaxf(m, __shfl_xor(m, off, 64));
        float inv = (m > 0.f) ? 127.f / m : 0.f;
        int q0 = max(-127, min(127, (int)rintf(w0 * inv)));
        int q1 = max(-127, min(127, (int)rintf(w1 * inv)));
        unsigned short pk = (unsigned short)((q0 & 0xff) | ((q1 & 0xff) << 8));
        *(unsigned short*)(Wq8 + (size_t)co * KTOT + ord * 128 + lane * 2) = pk;
        if (lane == 0) Wsc[ord * 128 + co] = m / 127.f;
    }
}

// ---------------- scans ------------------------------------------------------
__global__ __launch_bounds__(256) void scan1_kernel(const int* __restrict__ cnt,
                                                    int* __restrict__ rowPtr,
                                                    int* __restrict__ blkSum) {
    __shared__ int sh[256];
    const int t = threadIdx.x;
    const int i = blockIdx.x * 256 + t;
    int v = (i < V_NODES) ? cnt[i] : 0;
    sh[t] = v;
    __syncthreads();
    #pragma unroll
    for (int off = 1; off < 256; off <<= 1) {
        int u = (t >= off) ? sh[t - off] : 0;
        __syncthreads();
        sh[t] += u;
        __syncthreads();
    }
    if (i < V_NODES) rowPtr[i] = sh[t] - v;
    if (t == 255) blkSum[blockIdx.x] = sh[255];
}

__global__ __launch_bounds__(256) void scan23_kernel(const int* __restrict__ blkSum,
                                                     int* __restrict__ rowPtr,
                                                     int* __restrict__ cursor) {
    __shared__ int sh[256];
    const int t = threadIdx.x;
    int v = (t < SCAN_NBLK) ? blkSum[t] : 0;
    sh[t] = v;
    __syncthreads();
    #pragma unroll
    for (int off = 1; off < 256; off <<= 1) {
        int u = (t >= off) ? sh[t - off] : 0;
        __syncthreads();
        sh[t] += u;
        __syncthreads();
    }
    const int boff = sh[blockIdx.x] - blkSum[blockIdx.x];
    const int i = blockIdx.x * 256 + t;
    if (i < V_NODES) {
        int r = rowPtr[i] + boff;
        rowPtr[i] = r;
        cursor[i] = r;
    }
    if (blockIdx.x == 0 && t == 255) rowPtr[V_NODES] = sh[255];
}

// ---------------- prep2: quant_rows ∥ scatter (block-range dispatch) ---------
__global__ __launch_bounds__(256) void prep2_kernel(const unsigned short* __restrict__ xb,
                                                    signed char* __restrict__ xi,
                                                    float* __restrict__ xs,
                                                    const float* __restrict__ vals,
                                                    const int* __restrict__ rows,
                                                    const int* __restrict__ cols,
                                                    int* __restrict__ cursor,
                                                    EPair* __restrict__ ep, int E) {
    const int bid = blockIdx.x;
    if (bid < QUANT_BLOCKS) {
        // ---- quantize bf16 rows -> int8 + per-row scale ----
        const int wid = threadIdx.x >> 6;
        const int lane = threadIdx.x & 63;
        const int row = bid * 4 + wid;
        if (row >= V_NODES) return;
        uint4 q = ((const uint4*)xb)[(size_t)row * 64 + lane];
        unsigned int u[4] = {q.x, q.y, q.z, q.w};
        float f[8];
        #pragma unroll
        for (int j = 0; j < 4; ++j) {
            f[2*j+0] = bf2f((unsigned short)(u[j] & 0xffffu));
            f[2*j+1] = bf2f((unsigned short)(u[j] >> 16));
        }
        float m = 0.f;
        #pragma unroll
        for (int j = 0; j < 8; ++j) m = fmaxf(m, fabsf(f[j]));
        #pragma unroll
        for (int off = 1; off < 64; off <<= 1) m = fmaxf(m, __shfl_xor(m, off, 64));
        float inv = (m > 0.f) ? 127.f / m : 0.f;
        uint2 o; unsigned int ow[2] = {0u, 0u};
        #pragma unroll
        for (int j = 0; j < 8; ++j) {
            int si = (int)rintf(f[j] * inv);
            si = max(-127, min(127, si));
            ow[j >> 2] |= ((unsigned int)(si & 0xff)) << (8 * (j & 3));
        }
        o.x = ow[0]; o.y = ow[1];
        ((uint2*)xi)[(size_t)row * 64 + lane] = o;
        if (lane == 0) xs[row] = m / 127.f;
    } else {
        // ---- scatter edges into CSR slots ----
        int e = (bid - QUANT_BLOCKS) * 256 + threadIdx.x;
        if (e >= E) return;
        int r = rows[e];
        int pos = atomicAdd(&cursor[r], 1);
        EPair p; p.w = vals[e]; p.c = cols[e];
        ep[pos] = p;
    }
}

// ---------------- CSR SpMM: i8 in, i8 out -----------------------------------
__global__ __launch_bounds__(256) void spmm_i8_kernel(const EPair* __restrict__ ep,
                                                      const int* __restrict__ rowPtr,
                                                      const signed char* __restrict__ xi,
                                                      const float* __restrict__ xsc,
                                                      const signed char* __restrict__ oldi,
                                                      const float* __restrict__ oldsc,
                                                      signed char* __restrict__ yi,
                                                      float* __restrict__ ysc,
                                                      float alpha, int beta) {
    const int wid = threadIdx.x >> 6;
    const int lane = threadIdx.x & 63;
    const int row = blockIdx.x * 4 + wid;
    if (row >= V_NODES) return;
    const int s = rowPtr[row], e_end = rowPtr[row + 1];
    const uint2* __restrict__ xq = (const uint2*)xi;   // 64 x 8B per row

    float acc[8];
    #pragma unroll
    for (int j = 0; j < 8; ++j) acc[j] = 0.f;

    int e = s;
    for (; e + 3 < e_end; e += 4) {
        EPair p[4];
        #pragma unroll
        for (int i = 0; i < 4; ++i) p[i] = ep[e + i];
        float w[4];
        #pragma unroll
        for (int i = 0; i < 4; ++i) w[i] = p[i].w * xsc[p[i].c];
        uint2 q[4];
        #pragma unroll
        for (int i = 0; i < 4; ++i) q[i] = xq[(size_t)p[i].c * 64 + lane];
        #pragma unroll
        for (int i = 0; i < 4; ++i) {
            #pragma unroll
            for (int wd = 0; wd < 2; ++wd) {
                unsigned int uu = wd ? q[i].y : q[i].x;
                #pragma unroll
                for (int b = 0; b < 4; ++b) {
                    float xv = (float)((signed char)(uu >> (8 * b)));
                    acc[wd * 4 + b] += w[i] * xv;
                }
            }
        }
    }
    for (; e < e_end; ++e) {
        EPair p0 = ep[e];
        float w0 = p0.w * xsc[p0.c];
        uint2 q0 = xq[(size_t)p0.c * 64 + lane];
        #pragma unroll
        for (int wd = 0; wd < 2; ++wd) {
            unsigned int uu = wd ? q0.y : q0.x;
            #pragma unroll
            for (int b = 0; b < 4; ++b) {
                float xv = (float)((signed char)(uu >> (8 * b)));
                acc[wd * 4 + b] += w0 * xv;
            }
        }
    }

    float r[8];
    #pragma unroll
    for (int j = 0; j < 8; ++j) r[j] = alpha * acc[j];
    if (beta) {
        uint2 q = ((const uint2*)oldi)[(size_t)row * 64 + lane];
        const float os = oldsc[row];
        #pragma unroll
        for (int wd = 0; wd < 2; ++wd) {
            unsigned int uu = wd ? q.y : q.x;
            #pragma unroll
            for (int b = 0; b < 4; ++b)
                r[wd * 4 + b] -= os * (float)((signed char)(uu >> (8 * b)));
        }
    }

    float m = 0.f;
    #pragma unroll
    for (int j = 0; j < 8; ++j) m = fmaxf(m, fabsf(r[j]));
    #pragma unroll
    for (int off = 1; off < 64; off <<= 1) m = fmaxf(m, __shfl_xor(m, off, 64));
    float inv = (m > 0.f) ? 127.f / m : 0.f;
    unsigned int ow[2] = {0u, 0u};
    #pragma unroll
    for (int j = 0; j < 8; ++j) {
        int si = (int)rintf(r[j] * inv);
        si = max(-127, min(127, si));
        ow[j >> 2] |= ((unsigned int)(si & 0xff)) << (8 * (j & 3));
    }
    uint2 oi; oi.x = ow[0]; oi.y = ow[1];
    ((uint2*)yi)[(size_t)row * 64 + lane] = oi;
    if (lane == 0) ysc[row] = m / 127.f;
}

// ---------------- fused i8-MFMA GEMM, 8 waves (2v x 4co) --------------------
__global__ __launch_bounds__(512) void gemm_mfma_kernel(const signed char* __restrict__ Ti8,
                                                        const float* __restrict__ Tsc,
                                                        const signed char* __restrict__ Wq8,
                                                        const float* __restrict__ Wsc,
                                                        const float* __restrict__ bias,
                                                        float* __restrict__ out) {
    __shared__ signed char Abuf[3][128 * 64];   // 3 x 8 KB ring
    const int tid = threadIdx.x;
    const int lane = tid & 63;
    const int wid = tid >> 6;        // 0..7
    const int wr = wid >> 2;         // 0..1: v-half
    const int wc = wid & 3;          // 0..3: co-quarter
    const int v0 = blockIdx.x * 128;
    const int b = blockIdx.y;
    const int lr = lane & 15;
    const int lk = lane >> 4;

    // staging: 1 glds/thread. dest = tid*16 (linear); source chunk rotated.
    size_t gof;
    {
        int rl = tid >> 2;           // 0..127
        int ch = tid & 3;
        int rowg = v0 + rl;
        if (rowg >= V_NODES) rowg = V_NODES - 1;
        int srcch = (ch - ((rl >> 1) & 3)) & 3;
        gof = (size_t)rowg * FDIM + b * CIN + (size_t)(srcch << 4);
    }

    f32x4 accF[4][2];
    i32x4 accI[4][2];
    #pragma unroll
    for (int mf = 0; mf < 4; ++mf)
        #pragma unroll
        for (int nf = 0; nf < 2; ++nf) {
            accF[mf][nf] = (f32x4){0.f, 0.f, 0.f, 0.f};
            accI[mf][nf] = (i32x4){0, 0, 0, 0};
        }

    const signed char* Bb = Wq8 + (size_t)(wc * 32 + lr) * KTOT + lk * 16;

    // prologue: stage steps 0,1; preload B(0)
    #pragma unroll
    for (int st = 0; st < 2; ++st) {
        const size_t soff = (size_t)(st & 1) * 64;   // steps 0,1 are order 0
        __builtin_amdgcn_global_load_lds(
            (const __attribute__((address_space(1))) void*)(Ti8 + gof + soff),
            (__attribute__((address_space(3))) void*)(&Abuf[st][tid * 16]),
            16, 0, 0);
    }
    i32x4 bcur[2];
    #pragma unroll
    for (int nf = 0; nf < 2; ++nf)
        bcur[nf] = *(const i32x4*)(Bb + (size_t)nf * 16 * KTOT);
    f32x4 sv[4];
    float swv0 = 0.f, swv1 = 0.f;
    asm volatile("s_waitcnt vmcnt(0)" ::: "memory");
    asm volatile("s_barrier" ::: "memory");

    int curm = 0, stm = 2;
    #pragma unroll 1
    for (int s = 0; s < 10; ++s) {
        // 1) prefetch B(s+1) into registers (8 VGPR, i8)
        i32x4 bnxt[2];
        if (s < 9) {
            #pragma unroll
            for (int nf = 0; nf < 2; ++nf)
                bnxt[nf] = *(const i32x4*)(Bb + (size_t)nf * 16 * KTOT + (s + 1) * 64);
        }
        // 2) even steps: prefetch rescale factors used at step s+1 (ord = s/2)
        if (!(s & 1)) {
            const int ord = s >> 1;
            #pragma unroll
            for (int mf = 0; mf < 4; ++mf) {
                int base = v0 + wr * 64 + mf * 16 + lk * 4;
                if (base > V_NODES - 4) base = V_NODES - 4;
                sv[mf] = *(const f32x4*)(Tsc + (size_t)ord * V_NODES + base);
            }
            swv0 = Wsc[ord * 128 + wc * 32 + lr];
            swv1 = Wsc[ord * 128 + wc * 32 + 16 + lr];
        }
        __builtin_amdgcn_sched_barrier(0);
        // 3) stage step s+2 (stays in flight two iterations)
        if (s < 8) {
            const int sn = s + 2;
            const size_t soff = (size_t)(sn >> 1) * ((size_t)V_NODES * FDIM) + (size_t)((sn & 1) * 64);
            __builtin_amdgcn_global_load_lds(
                (const __attribute__((address_space(1))) void*)(Ti8 + gof + soff),
                (__attribute__((address_space(3))) void*)(&Abuf[stm][tid * 16]),
                16, 0, 0);
        }
        // 4) compute: b128 rotated A reads -> i8 MFMA with bcur (registers)
        const signed char* Ab = &Abuf[curm][0];
        i32x4 a[4];
        #pragma unroll
        for (int mf = 0; mf < 4; ++mf) {
            int rl = wr * 64 + mf * 16 + lr;
            int phys = rl * 64 + (((lk + (rl >> 1)) & 3) << 4);
            a[mf] = *(const i32x4*)(Ab + phys);
        }
        #pragma unroll
        for (int mf = 0; mf < 4; ++mf)
            #pragma unroll
            for (int nf = 0; nf < 2; ++nf)
                accI[mf][nf] = __builtin_amdgcn_mfma_i32_16x16x64_i8(a[mf], bcur[nf], accI[mf][nf], 0, 0, 0);
        // 5) order boundary: rescale i32 -> f32 (factors prefetched at s-1)
        if (s & 1) {
            #pragma unroll
            for (int mf = 0; mf < 4; ++mf)
                #pragma unroll
                for (int nf = 0; nf < 2; ++nf) {
                    float sw = nf ? swv1 : swv0;
                    #pragma unroll
                    for (int e = 0; e < 4; ++e)
                        accF[mf][nf][e] += (float)accI[mf][nf][e] * (sv[mf][e] * sw);
                    accI[mf][nf] = (i32x4){0, 0, 0, 0};
                }
        }
        // 6) copy prefetched B (compiler's wait here drains B(s+1)+stage(s+1))
        if (s < 9) {
            bcur[0] = bnxt[0];
            bcur[1] = bnxt[1];
        }
        asm volatile("s_barrier" ::: "memory");
        curm = (curm == 2) ? 0 : curm + 1;
        stm  = (stm == 2) ? 0 : stm + 1;
    }

    // --- epilogue: transpose through LDS (reuse ring), coalesced f32x4 stores
    float* lds_f = (float*)&Abuf[0][0];            // 32 co x 132 f32 = 16.9 KB < 24 KB
    const float bs0 = bias[wc * 32 + lr];
    const float bs1 = bias[wc * 32 + 16 + lr];
    #pragma unroll
    for (int p = 0; p < 4; ++p) {
        if (wc == p) {
            #pragma unroll
            for (int mf = 0; mf < 4; ++mf)
                #pragma unroll
                for (int nf = 0; nf < 2; ++nf) {
                    int co_l = nf * 16 + lr;
                    int vbase = wr * 64 + mf * 16 + lk * 4;
                    f32x4 val = accF[mf][nf];
                    float bs = nf ? bs1 : bs0;
                    val[0] += bs; val[1] += bs; val[2] += bs; val[3] += bs;
                    *(f32x4*)(lds_f + co_l * 132 + vbase) = val;
                }
        }
        __syncthreads();
        #pragma unroll
        for (int i = 0; i < 2; ++i) {
            int flat = i * 512 + tid;
            int co_l = flat >> 5;
            int v4 = flat & 31;
            int v = v0 + v4 * 4;
            if (v < V_NODES) {
                f32x4 val = *(const f32x4*)(lds_f + co_l * 132 + v4 * 4);
                *(f32x4*)(out + (size_t)(b * COUT + p * 32 + co_l) * V_NODES + v) = val;
            }
        }
        __syncthreads();
    }
}

extern "C" void kernel_launch(void* const* d_in, const int* in_sizes, int n_in,
                              void* d_out, int out_size, void* d_ws, size_t ws_size,
                              hipStream_t stream) {
    const float* x    = (const float*)d_in[0];
    const float* vals = (const float*)d_in[1];
    const float* W    = (const float*)d_in[2];
    const float* bias = (const float*)d_in[3];
    const int* rows   = (const int*)d_in[4];
    const int* cols   = (const int*)d_in[5];
    const int E = in_sizes[1];
    float* out = (float*)d_out;

    // workspace: bf16 T0 scratch, i8 T0..T4, scales (+pad), Wq8, Wsc, edges, CSR
    unsigned short* T0bf = (unsigned short*)d_ws;                      // V*512 bf16
    signed char* i8T = (signed char*)(T0bf + (size_t)V_NODES * FDIM);  // 5 * V*512
    float* sc  = (float*)(i8T + (size_t)KORD * V_NODES * FDIM);        // 5*V + 64 pad
    signed char* Wq8 = (signed char*)(sc + (size_t)KORD * V_NODES + 64);  // 128*640
    float* Wsc = (float*)(Wq8 + (size_t)COUT * KTOT);                  // 640
    EPair* ep     = (EPair*)(Wsc + KORD * COUT);
    int*   rowPtr = (int*)(ep + E);
    int*   cursor = rowPtr + V_NODES + 1;
    int*   cnt    = cursor + V_NODES;
    int*   blkSum = cnt + V_NODES;            // SCAN_NBLK

    signed char* i8T0 = i8T;
    signed char* i8T1 = i8T + 1 * (size_t)V_NODES * FDIM;
    signed char* i8T2 = i8T + 2 * (size_t)V_NODES * FDIM;
    signed char* i8T3 = i8T + 3 * (size_t)V_NODES * FDIM;
    signed char* i8T4 = i8T + 4 * (size_t)V_NODES * FDIM;
    float* sc0 = sc + 0 * (size_t)V_NODES;
    float* sc1 = sc + 1 * (size_t)V_NODES;
    float* sc2 = sc + 2 * (size_t)V_NODES;
    float* sc3 = sc + 3 * (size_t)V_NODES;
    float* sc4 = sc + 4 * (size_t)V_NODES;

    const int histBlocks = (E + 255) / 256;
    const int spB4 = (V_NODES + 3) / 4;

    // prep1: transpose ∥ hist ∥ convw_q8
    hipMemsetAsync(cnt, 0, V_NODES * sizeof(int), stream);
    prep1_kernel<<<TR_BLOCKS + histBlocks + CONVW_BLOCKS, 256, 0, stream>>>(
        x, T0bf, rows, cnt, E, histBlocks, W, Wq8, Wsc);
    scan1_kernel<<<SCAN_NBLK, 256, 0, stream>>>(cnt, rowPtr, blkSum);
    scan23_kernel<<<SCAN_NBLK, 256, 0, stream>>>(blkSum, rowPtr, cursor);
    // prep2: quant_rows ∥ scatter
    prep2_kernel<<<QUANT_BLOCKS + histBlocks, 256, 0, stream>>>(
        T0bf, i8T0, sc0, vals, rows, cols, cursor, ep, E);

    // Chebyshev recurrence — all state in i8 + per-row scale
    spmm_i8_kernel<<<spB4, 256, 0, stream>>>(ep, rowPtr, i8T0, sc0, i8T0, sc0, i8T1, sc1, 1.f, 0);
    spmm_i8_kernel<<<spB4, 256, 0, stream>>>(ep, rowPtr, i8T1, sc1, i8T0, sc0, i8T2, sc2, 2.f, 1);
    spmm_i8_kernel<<<spB4, 256, 0, stream>>>(ep, rowPtr, i8T2, sc2, i8T1, sc1, i8T3, sc3, 2.f, 1);
    spmm_i8_kernel<<<spB4, 256, 0, stream>>>(ep, rowPtr, i8T3, sc3, i8T2, sc2, i8T4, sc4, 2.f, 1);

    // fused contraction over all 5 orders (i8 MFMA, 8 waves)
    dim3 gg((V_NODES + 127) / 128, BATCH);
    gemm_mfma_kernel<<<gg, 512, 0, stream>>>(i8T, sc, Wq8, Wsc, bias, out);
}